// Round 1
// baseline (2962.618 us; speedup 1.0000x reference)
//
#include <hip/hip_runtime.h>
#include <hip/hip_bf16.h>
#include <math.h>

#define BB 256
#define TT 64
#define EE 2048
#define DD 512
#define AA 512
#define VV 10000
#define EMBD 256
#define KLSTM (EE + EMBD + DD)   // 2816
#define N4D (4 * DD)             // 2048

__device__ __forceinline__ float sigf(float x) { return 1.f / (1.f + expf(-x)); }

// ---------------- q = hidden @ w1 + b1 + b2 (fold both biases) ----------------
// grid(B), block(256); each thread computes 2 adjacent a's via float2 weight loads
__global__ void k_q(const float* __restrict__ hidden, const float* __restrict__ w1,
                    const float* __restrict__ b1, const float* __restrict__ b2,
                    float* __restrict__ qq) {
    __shared__ float hs[DD];
    const int b = blockIdx.x, tid = threadIdx.x;
    {
        float2 hv = *(const float2*)&hidden[(size_t)b * DD + 2 * tid];
        hs[2 * tid] = hv.x; hs[2 * tid + 1] = hv.y;
    }
    __syncthreads();
    const int a0 = 2 * tid;
    float2 acc = {0.f, 0.f};
    #pragma unroll 4
    for (int k = 0; k < DD; ++k) {
        float2 w = *(const float2*)&w1[(size_t)k * AA + a0];
        float h = hs[k];
        acc.x = fmaf(h, w.x, acc.x);
        acc.y = fmaf(h, w.y, acc.y);
    }
    qq[(size_t)b * AA + a0]     = acc.x + b1[a0]     + b2[a0];
    qq[(size_t)b * AA + a0 + 1] = acc.y + b1[a0 + 1] + b2[a0 + 1];
}

// ---- score[b,t] = tanh(q[b,:] + enc[b,t,:] @ w2) . v + bv  (the 34 GFLOP GEMM) ----
// grid(T/16, B), block(256). Each block: 16 t's, all 512 a's (2 per thread).
__global__ void k_score(const float* __restrict__ enc, const float* __restrict__ w2,
                        const float* __restrict__ qq, const float* __restrict__ vvec,
                        const float* __restrict__ bv, float* __restrict__ score) {
    const int TTILE = 16, ET = 64;
    __shared__ float es[TTILE][ET];
    __shared__ float wred[4 * TTILE];
    const int b = blockIdx.y;
    const int t0 = blockIdx.x * TTILE;
    const int tid = threadIdx.x;
    const int a0 = 2 * tid;

    const float q0 = qq[(size_t)b * AA + a0];
    const float q1 = qq[(size_t)b * AA + a0 + 1];
    const float v0 = vvec[a0];
    const float v1 = vvec[a0 + 1];

    float acc[TTILE][2];
    #pragma unroll
    for (int t = 0; t < TTILE; ++t) { acc[t][0] = 0.f; acc[t][1] = 0.f; }

    const float* encb = enc + (size_t)(b * TT + t0) * EE;

    for (int e0 = 0; e0 < EE; e0 += ET) {
        #pragma unroll
        for (int r = 0; r < 4; ++r) {
            int flat = r * 256 + tid;
            int tt = flat >> 6;
            int ee = flat & 63;
            es[tt][ee] = encb[(size_t)tt * EE + e0 + ee];
        }
        __syncthreads();
        for (int e = 0; e < ET; e += 4) {
            const float2 wA = *(const float2*)&w2[(size_t)(e0 + e) * AA + a0];
            const float2 wBv = *(const float2*)&w2[(size_t)(e0 + e + 1) * AA + a0];
            const float2 wC = *(const float2*)&w2[(size_t)(e0 + e + 2) * AA + a0];
            const float2 wDv = *(const float2*)&w2[(size_t)(e0 + e + 3) * AA + a0];
            #pragma unroll
            for (int t = 0; t < TTILE; ++t) {
                float4 ev = *(const float4*)&es[t][e];
                acc[t][0] = fmaf(ev.x, wA.x, acc[t][0]);
                acc[t][1] = fmaf(ev.x, wA.y, acc[t][1]);
                acc[t][0] = fmaf(ev.y, wBv.x, acc[t][0]);
                acc[t][1] = fmaf(ev.y, wBv.y, acc[t][1]);
                acc[t][0] = fmaf(ev.z, wC.x, acc[t][0]);
                acc[t][1] = fmaf(ev.z, wC.y, acc[t][1]);
                acc[t][0] = fmaf(ev.w, wDv.x, acc[t][0]);
                acc[t][1] = fmaf(ev.w, wDv.y, acc[t][1]);
            }
        }
        __syncthreads();
    }

    const int lane = tid & 63, wv = tid >> 6;
    #pragma unroll
    for (int t = 0; t < TTILE; ++t) {
        float x = tanhf(q0 + acc[t][0]) * v0 + tanhf(q1 + acc[t][1]) * v1;
        #pragma unroll
        for (int off = 32; off >= 1; off >>= 1) x += __shfl_down(x, off, 64);
        if (lane == 0) wred[wv * TTILE + t] = x;
    }
    __syncthreads();
    if (tid < TTILE) {
        float s = wred[tid] + wred[TTILE + tid] + wred[2 * TTILE + tid] + wred[3 * TTILE + tid] + bv[0];
        score[(size_t)b * TT + t0 + tid] = s;
    }
}

// ---------------- softmax over t + context = sum_t attn * enc ----------------
// grid(2, B), block(256): each block does 1024 e's (float4 per thread)
__global__ void k_context(const float* __restrict__ enc, const float* __restrict__ score,
                          float* __restrict__ ctx) {
    __shared__ float attn[TT];
    const int b = blockIdx.y;
    const int tid = threadIdx.x;
    if (tid < 64) {
        float s = score[(size_t)b * TT + tid];
        float m = s;
        #pragma unroll
        for (int off = 1; off < 64; off <<= 1) m = fmaxf(m, __shfl_xor(m, off, 64));
        float p = expf(s - m);
        float sum = p;
        #pragma unroll
        for (int off = 1; off < 64; off <<= 1) sum += __shfl_xor(sum, off, 64);
        attn[tid] = p / sum;
    }
    __syncthreads();
    const int e = blockIdx.x * 1024 + tid * 4;
    const float* encb = enc + (size_t)b * TT * EE + e;
    float4 acc = {0.f, 0.f, 0.f, 0.f};
    #pragma unroll 4
    for (int t = 0; t < TT; ++t) {
        float a = attn[t];
        float4 ev = *(const float4*)&encb[(size_t)t * EE];
        acc.x = fmaf(a, ev.x, acc.x);
        acc.y = fmaf(a, ev.y, acc.y);
        acc.z = fmaf(a, ev.z, acc.z);
        acc.w = fmaf(a, ev.w, acc.w);
    }
    *(float4*)&ctx[(size_t)b * EE + e] = acc;
}

// ------- z = [ctx, emb[c]] @ wx + hidden @ wh + bl  (K = 2048+256+512 = 2816) -------
// grid(2048/64, B/32), block(256): j-tile 64 (tx), b-tile 32 (8 rows per thread)
__global__ void k_z(const float* __restrict__ ctx, const float* __restrict__ emb,
                    const int* __restrict__ cidx, const float* __restrict__ hidden,
                    const float* __restrict__ wx, const float* __restrict__ wh,
                    const float* __restrict__ bl, float* __restrict__ z) {
    __shared__ float as[32][32];
    __shared__ int cbs[32];
    const int j0 = blockIdx.x * 64;
    const int b0 = blockIdx.y * 32;
    const int tid = threadIdx.x;
    const int tx = tid & 63, ty = tid >> 6;
    const int j = j0 + tx;

    if (tid < 32) cbs[tid] = cidx[b0 + tid];

    float acc[8];
    #pragma unroll
    for (int r = 0; r < 8; ++r) acc[r] = 0.f;

    for (int k0 = 0; k0 < KLSTM; k0 += 32) {
        __syncthreads();
        #pragma unroll
        for (int r = 0; r < 4; ++r) {
            int flat = r * 256 + tid;
            int bb = flat >> 5;
            int kk = flat & 31;
            int kg = k0 + kk;
            int bg = b0 + bb;
            float val;
            if (kg < EE) val = ctx[(size_t)bg * EE + kg];
            else if (kg < EE + EMBD) val = emb[(size_t)cbs[bb] * EMBD + (kg - EE)];
            else val = hidden[(size_t)bg * DD + (kg - EE - EMBD)];
            as[bb][kk] = val;
        }
        __syncthreads();
        for (int kk = 0; kk < 32; kk += 4) {
            int kg = k0 + kk;
            float w0, w1v, w2v, w3v;
            if (kg < EE + EMBD) {
                w0  = wx[(size_t)kg * N4D + j];
                w1v = wx[(size_t)(kg + 1) * N4D + j];
                w2v = wx[(size_t)(kg + 2) * N4D + j];
                w3v = wx[(size_t)(kg + 3) * N4D + j];
            } else {
                int kh = kg - EE - EMBD;
                w0  = wh[(size_t)kh * N4D + j];
                w1v = wh[(size_t)(kh + 1) * N4D + j];
                w2v = wh[(size_t)(kh + 2) * N4D + j];
                w3v = wh[(size_t)(kh + 3) * N4D + j];
            }
            #pragma unroll
            for (int r = 0; r < 8; ++r) {
                int bb = ty + 4 * r;
                float4 av = *(const float4*)&as[bb][kk];
                acc[r] = fmaf(av.x, w0, acc[r]);
                acc[r] = fmaf(av.y, w1v, acc[r]);
                acc[r] = fmaf(av.z, w2v, acc[r]);
                acc[r] = fmaf(av.w, w3v, acc[r]);
            }
        }
    }
    const float blj = bl[j];
    #pragma unroll
    for (int r = 0; r < 8; ++r) {
        int bg = b0 + ty + 4 * r;
        z[(size_t)bg * N4D + j] = acc[r] + blj;
    }
}

// ---------------- LSTM gates: c_new, h_new ----------------
__global__ void k_gates(const float* __restrict__ z, const float* __restrict__ carry,
                        float* __restrict__ hout, float* __restrict__ cout) {
    const int b = blockIdx.x, tid = threadIdx.x;
    #pragma unroll
    for (int r = 0; r < 2; ++r) {
        int d = tid + r * 256;
        float zi = z[(size_t)b * N4D + d];
        float zf = z[(size_t)b * N4D + DD + d];
        float zg = z[(size_t)b * N4D + 2 * DD + d];
        float zo = z[(size_t)b * N4D + 3 * DD + d];
        float c = carry[(size_t)b * DD + d];
        float cn = sigf(zf) * c + sigf(zi) * tanhf(zg);
        float hn = sigf(zo) * tanhf(cn);
        cout[(size_t)b * DD + d] = cn;
        hout[(size_t)b * DD + d] = hn;
    }
}

// ---------------- logits = h_new @ wp + bp ----------------
// grid(ceil(V/64), B/32), block(256): j-tile 64, b-tile 32 (8 rows per thread)
__global__ void k_logits(const float* __restrict__ hnew, const float* __restrict__ wp,
                         const float* __restrict__ bp, float* __restrict__ logits) {
    __shared__ float hs[32][64];
    const int j0 = blockIdx.x * 64;
    const int b0 = blockIdx.y * 32;
    const int tid = threadIdx.x;
    const int tx = tid & 63, ty = tid >> 6;
    const int j = j0 + tx;
    const int jc = (j < VV) ? j : (VV - 1);

    float acc[8];
    #pragma unroll
    for (int r = 0; r < 8; ++r) acc[r] = 0.f;

    for (int k0 = 0; k0 < DD; k0 += 64) {
        __syncthreads();
        #pragma unroll
        for (int r = 0; r < 8; ++r) {
            int flat = r * 256 + tid;
            int bb = flat >> 6;
            int kk = flat & 63;
            hs[bb][kk] = hnew[(size_t)(b0 + bb) * DD + k0 + kk];
        }
        __syncthreads();
        for (int kk = 0; kk < 64; kk += 4) {
            int kg = k0 + kk;
            float w0  = wp[(size_t)kg * VV + jc];
            float w1v = wp[(size_t)(kg + 1) * VV + jc];
            float w2v = wp[(size_t)(kg + 2) * VV + jc];
            float w3v = wp[(size_t)(kg + 3) * VV + jc];
            #pragma unroll
            for (int r = 0; r < 8; ++r) {
                int bb = ty + 4 * r;
                float4 hv = *(const float4*)&hs[bb][kk];
                acc[r] = fmaf(hv.x, w0, acc[r]);
                acc[r] = fmaf(hv.y, w1v, acc[r]);
                acc[r] = fmaf(hv.z, w2v, acc[r]);
                acc[r] = fmaf(hv.w, w3v, acc[r]);
            }
        }
    }
    if (j < VV) {
        const float bpj = bp[j];
        #pragma unroll
        for (int r = 0; r < 8; ++r) {
            int bg = b0 + ty + 4 * r;
            logits[(size_t)bg * VV + j] = acc[r] + bpj;
        }
    }
}

extern "C" void kernel_launch(void* const* d_in, const int* in_sizes, int n_in,
                              void* d_out, int out_size, void* d_ws, size_t ws_size,
                              hipStream_t stream) {
    const int*   cidx   = (const int*)d_in[0];
    const float* hidden = (const float*)d_in[1];
    const float* carry  = (const float*)d_in[2];
    const float* enc    = (const float*)d_in[3];
    const float* emb    = (const float*)d_in[4];
    const float* w1     = (const float*)d_in[5];
    const float* b1     = (const float*)d_in[6];
    const float* w2     = (const float*)d_in[7];
    const float* b2     = (const float*)d_in[8];
    const float* vvec   = (const float*)d_in[9];
    const float* bv     = (const float*)d_in[10];
    const float* wx     = (const float*)d_in[11];
    const float* wh     = (const float*)d_in[12];
    const float* bl     = (const float*)d_in[13];
    const float* wp     = (const float*)d_in[14];
    const float* bp     = (const float*)d_in[15];

    float* out    = (float*)d_out;
    float* logits = out;
    float* hout   = out + (size_t)BB * VV;
    float* cout   = hout + (size_t)BB * DD;

    float* ws    = (float*)d_ws;
    float* qq    = ws;                         // B*A      = 131072
    float* score = qq + (size_t)BB * AA;       // B*T      = 16384
    float* ctx   = score + (size_t)BB * TT;    // B*E      = 524288
    float* z     = ctx + (size_t)BB * EE;      // B*4D     = 524288

    hipLaunchKernelGGL(k_q,       dim3(BB),                 dim3(256), 0, stream, hidden, w1, b1, b2, qq);
    hipLaunchKernelGGL(k_score,   dim3(TT / 16, BB),        dim3(256), 0, stream, enc, w2, qq, vvec, bv, score);
    hipLaunchKernelGGL(k_context, dim3(2, BB),              dim3(256), 0, stream, enc, score, ctx);
    hipLaunchKernelGGL(k_z,       dim3(N4D / 64, BB / 32),  dim3(256), 0, stream, ctx, emb, cidx, hidden, wx, wh, bl, z);
    hipLaunchKernelGGL(k_gates,   dim3(BB),                 dim3(256), 0, stream, z, carry, hout, cout);
    hipLaunchKernelGGL(k_logits,  dim3((VV + 63) / 64, BB / 32), dim3(256), 0, stream, hout, wp, bp, logits);
}

// Round 2
// 899.528 us; speedup vs baseline: 3.2935x; 3.2935x over previous
//
#include <hip/hip_runtime.h>
#include <hip/hip_bf16.h>
#include <math.h>

#define BB 256
#define TT 64
#define EE 2048
#define DD 512
#define AA 512
#define VV 10000
#define EMBD 256
#define KLSTM (EE + EMBD + DD)   // 2816
#define N4D (4 * DD)             // 2048

__device__ __forceinline__ float sigf(float x) { return 1.f / (1.f + expf(-x)); }

// ---------------- q = hidden @ w1 + b1 + b2 (fold both biases) ----------------
__global__ void k_q(const float* __restrict__ hidden, const float* __restrict__ w1,
                    const float* __restrict__ b1, const float* __restrict__ b2,
                    float* __restrict__ qq) {
    __shared__ float hs[DD];
    const int b = blockIdx.x, tid = threadIdx.x;
    {
        float2 hv = *(const float2*)&hidden[(size_t)b * DD + 2 * tid];
        hs[2 * tid] = hv.x; hs[2 * tid + 1] = hv.y;
    }
    __syncthreads();
    const int a0 = 2 * tid;
    float2 acc = {0.f, 0.f};
    #pragma unroll 4
    for (int k = 0; k < DD; ++k) {
        float2 w = *(const float2*)&w1[(size_t)k * AA + a0];
        float h = hs[k];
        acc.x = fmaf(h, w.x, acc.x);
        acc.y = fmaf(h, w.y, acc.y);
    }
    qq[(size_t)b * AA + a0]     = acc.x + b1[a0]     + b2[a0];
    qq[(size_t)b * AA + a0 + 1] = acc.y + b1[a0 + 1] + b2[a0 + 1];
}

// ---- score[b,t] = tanh(q[b,:] + enc[b,t,:] @ w2) . v + bv ----
__global__ void k_score(const float* __restrict__ enc, const float* __restrict__ w2,
                        const float* __restrict__ qq, const float* __restrict__ vvec,
                        const float* __restrict__ bv, float* __restrict__ score) {
    const int TTILE = 16, ET = 64;
    __shared__ float es[TTILE][ET];
    __shared__ float wred[4 * TTILE];
    const int b = blockIdx.y;
    const int t0 = blockIdx.x * TTILE;
    const int tid = threadIdx.x;
    const int a0 = 2 * tid;

    const float q0 = qq[(size_t)b * AA + a0];
    const float q1 = qq[(size_t)b * AA + a0 + 1];
    const float v0 = vvec[a0];
    const float v1 = vvec[a0 + 1];

    float acc[TTILE][2];
    #pragma unroll
    for (int t = 0; t < TTILE; ++t) { acc[t][0] = 0.f; acc[t][1] = 0.f; }

    const float* encb = enc + (size_t)(b * TT + t0) * EE;

    for (int e0 = 0; e0 < EE; e0 += ET) {
        #pragma unroll
        for (int r = 0; r < 4; ++r) {
            int flat = r * 256 + tid;
            int tt = flat >> 6;
            int ee = flat & 63;
            es[tt][ee] = encb[(size_t)tt * EE + e0 + ee];
        }
        __syncthreads();
        for (int e = 0; e < ET; e += 4) {
            const float2 wA = *(const float2*)&w2[(size_t)(e0 + e) * AA + a0];
            const float2 wBv = *(const float2*)&w2[(size_t)(e0 + e + 1) * AA + a0];
            const float2 wC = *(const float2*)&w2[(size_t)(e0 + e + 2) * AA + a0];
            const float2 wDv = *(const float2*)&w2[(size_t)(e0 + e + 3) * AA + a0];
            #pragma unroll
            for (int t = 0; t < TTILE; ++t) {
                float4 ev = *(const float4*)&es[t][e];
                acc[t][0] = fmaf(ev.x, wA.x, acc[t][0]);
                acc[t][1] = fmaf(ev.x, wA.y, acc[t][1]);
                acc[t][0] = fmaf(ev.y, wBv.x, acc[t][0]);
                acc[t][1] = fmaf(ev.y, wBv.y, acc[t][1]);
                acc[t][0] = fmaf(ev.z, wC.x, acc[t][0]);
                acc[t][1] = fmaf(ev.z, wC.y, acc[t][1]);
                acc[t][0] = fmaf(ev.w, wDv.x, acc[t][0]);
                acc[t][1] = fmaf(ev.w, wDv.y, acc[t][1]);
            }
        }
        __syncthreads();
    }

    const int lane = tid & 63, wv = tid >> 6;
    #pragma unroll
    for (int t = 0; t < TTILE; ++t) {
        float x = tanhf(q0 + acc[t][0]) * v0 + tanhf(q1 + acc[t][1]) * v1;
        #pragma unroll
        for (int off = 32; off >= 1; off >>= 1) x += __shfl_down(x, off, 64);
        if (lane == 0) wred[wv * TTILE + t] = x;
    }
    __syncthreads();
    if (tid < TTILE) {
        float s = wred[tid] + wred[TTILE + tid] + wred[2 * TTILE + tid] + wred[3 * TTILE + tid] + bv[0];
        score[(size_t)b * TT + t0 + tid] = s;
    }
}

// ---------------- softmax over t + context = sum_t attn * enc ----------------
__global__ void k_context(const float* __restrict__ enc, const float* __restrict__ score,
                          float* __restrict__ ctx) {
    __shared__ float attn[TT];
    const int b = blockIdx.y;
    const int tid = threadIdx.x;
    if (tid < 64) {
        float s = score[(size_t)b * TT + tid];
        float m = s;
        #pragma unroll
        for (int off = 1; off < 64; off <<= 1) m = fmaxf(m, __shfl_xor(m, off, 64));
        float p = expf(s - m);
        float sum = p;
        #pragma unroll
        for (int off = 1; off < 64; off <<= 1) sum += __shfl_xor(sum, off, 64);
        attn[tid] = p / sum;
    }
    __syncthreads();
    const int e = blockIdx.x * 1024 + tid * 4;
    const float* encb = enc + (size_t)b * TT * EE + e;
    float4 acc = {0.f, 0.f, 0.f, 0.f};
    #pragma unroll 4
    for (int t = 0; t < TT; ++t) {
        float a = attn[t];
        float4 ev = *(const float4*)&encb[(size_t)t * EE];
        acc.x = fmaf(a, ev.x, acc.x);
        acc.y = fmaf(a, ev.y, acc.y);
        acc.z = fmaf(a, ev.z, acc.z);
        acc.w = fmaf(a, ev.w, acc.w);
    }
    *(float4*)&ctx[(size_t)b * EE + e] = acc;
}

// ------- z = [ctx, emb[c], hidden] @ [wx; wh] + bl  (K = 2816, both tiles in LDS) -------
// grid(N4D/64 = 32, BB/32 = 8), block(256) = (tx 0..15 over j/4) x (ty 0..15 over b/2).
// Thread tile: 2 b-rows x 4 j-cols in two float4 accumulators (pure registers).
// K-tile = 64; never straddles the 2048 (ctx|emb) or 2304 (emb|hidden) boundaries.
#define ZBM 32
#define ZBN 64
#define ZBK 64
__global__ void k_z(const float* __restrict__ ctx, const float* __restrict__ emb,
                    const int* __restrict__ cidx, const float* __restrict__ hidden,
                    const float* __restrict__ wx, const float* __restrict__ wh,
                    const float* __restrict__ bl, float* __restrict__ z) {
    __shared__ float As[ZBM][ZBK + 4];   // +4 pad keeps 16B alignment, breaks bank stride
    __shared__ float Ws[ZBK][ZBN];
    __shared__ int cbs[ZBM];
    const int tid = threadIdx.x;
    const int tx = tid & 15, ty = tid >> 4;
    const int j0 = blockIdx.x * ZBN;
    const int b0 = blockIdx.y * ZBM;

    if (tid < ZBM) cbs[tid] = cidx[b0 + tid];

    float4 acc0 = {0.f, 0.f, 0.f, 0.f};
    float4 acc1 = {0.f, 0.f, 0.f, 0.f};

    for (int k0 = 0; k0 < KLSTM; k0 += ZBK) {
        __syncthreads();
        // A tile: 32 rows x 64 k (2048 floats, 8 per thread), coalesced along k
        #pragma unroll
        for (int i = 0; i < 8; ++i) {
            int flat = i * 256 + tid;
            int bb = flat >> 6;
            int kk = flat & 63;
            int kg = k0 + kk;
            int bg = b0 + bb;
            float val;
            if (kg < EE)            val = ctx[(size_t)bg * EE + kg];
            else if (kg < EE + EMBD) val = emb[(size_t)cbs[bb] * EMBD + (kg - EE)];
            else                     val = hidden[(size_t)bg * DD + (kg - EE - EMBD)];
            As[bb][kk] = val;
        }
        // W tile: 64 rows x 64 j (1024 float4s, 4 per thread), coalesced float4
        #pragma unroll
        for (int i = 0; i < 4; ++i) {
            int flat = i * 256 + tid;
            int row = flat >> 4;
            int c4 = flat & 15;
            int kg = k0 + row;
            const float* wrow = (kg < EE + EMBD)
                ? &wx[(size_t)kg * N4D + j0]
                : &wh[(size_t)(kg - EE - EMBD) * N4D + j0];
            *(float4*)&Ws[row][c4 * 4] = *(const float4*)&wrow[c4 * 4];
        }
        __syncthreads();
        #pragma unroll 4
        for (int kk = 0; kk < ZBK; kk += 4) {
            float4 a0 = *(const float4*)&As[2 * ty][kk];
            float4 a1 = *(const float4*)&As[2 * ty + 1][kk];
            const float a0v[4] = {a0.x, a0.y, a0.z, a0.w};
            const float a1v[4] = {a1.x, a1.y, a1.z, a1.w};
            #pragma unroll
            for (int u = 0; u < 4; ++u) {
                float4 w = *(const float4*)&Ws[kk + u][4 * tx];
                acc0.x = fmaf(a0v[u], w.x, acc0.x);
                acc0.y = fmaf(a0v[u], w.y, acc0.y);
                acc0.z = fmaf(a0v[u], w.z, acc0.z);
                acc0.w = fmaf(a0v[u], w.w, acc0.w);
                acc1.x = fmaf(a1v[u], w.x, acc1.x);
                acc1.y = fmaf(a1v[u], w.y, acc1.y);
                acc1.z = fmaf(a1v[u], w.z, acc1.z);
                acc1.w = fmaf(a1v[u], w.w, acc1.w);
            }
        }
    }

    const int j = j0 + 4 * tx;
    float4 bb4 = *(const float4*)&bl[j];
    acc0.x += bb4.x; acc0.y += bb4.y; acc0.z += bb4.z; acc0.w += bb4.w;
    acc1.x += bb4.x; acc1.y += bb4.y; acc1.z += bb4.z; acc1.w += bb4.w;
    *(float4*)&z[(size_t)(b0 + 2 * ty) * N4D + j]     = acc0;
    *(float4*)&z[(size_t)(b0 + 2 * ty + 1) * N4D + j] = acc1;
}

// ---------------- LSTM gates: c_new, h_new ----------------
__global__ void k_gates(const float* __restrict__ z, const float* __restrict__ carry,
                        float* __restrict__ hout, float* __restrict__ cout) {
    const int b = blockIdx.x, tid = threadIdx.x;
    #pragma unroll
    for (int r = 0; r < 2; ++r) {
        int d = tid + r * 256;
        float zi = z[(size_t)b * N4D + d];
        float zf = z[(size_t)b * N4D + DD + d];
        float zg = z[(size_t)b * N4D + 2 * DD + d];
        float zo = z[(size_t)b * N4D + 3 * DD + d];
        float c = carry[(size_t)b * DD + d];
        float cn = sigf(zf) * c + sigf(zi) * tanhf(zg);
        float hn = sigf(zo) * tanhf(cn);
        cout[(size_t)b * DD + d] = cn;
        hout[(size_t)b * DD + d] = hn;
    }
}

// ---------------- logits = h_new @ wp + bp ----------------
__global__ void k_logits(const float* __restrict__ hnew, const float* __restrict__ wp,
                         const float* __restrict__ bp, float* __restrict__ logits) {
    __shared__ float hs[32][64];
    const int j0 = blockIdx.x * 64;
    const int b0 = blockIdx.y * 32;
    const int tid = threadIdx.x;
    const int tx = tid & 63, ty = tid >> 6;
    const int j = j0 + tx;
    const int jc = (j < VV) ? j : (VV - 1);

    float acc[8];
    #pragma unroll
    for (int r = 0; r < 8; ++r) acc[r] = 0.f;

    for (int k0 = 0; k0 < DD; k0 += 64) {
        __syncthreads();
        #pragma unroll
        for (int r = 0; r < 8; ++r) {
            int flat = r * 256 + tid;
            int bb = flat >> 6;
            int kk = flat & 63;
            hs[bb][kk] = hnew[(size_t)(b0 + bb) * DD + k0 + kk];
        }
        __syncthreads();
        for (int kk = 0; kk < 64; kk += 4) {
            int kg = k0 + kk;
            float w0  = wp[(size_t)kg * VV + jc];
            float w1v = wp[(size_t)(kg + 1) * VV + jc];
            float w2v = wp[(size_t)(kg + 2) * VV + jc];
            float w3v = wp[(size_t)(kg + 3) * VV + jc];
            #pragma unroll
            for (int r = 0; r < 8; ++r) {
                int bb = ty + 4 * r;
                float4 hv = *(const float4*)&hs[bb][kk];
                acc[r] = fmaf(hv.x, w0, acc[r]);
                acc[r] = fmaf(hv.y, w1v, acc[r]);
                acc[r] = fmaf(hv.z, w2v, acc[r]);
                acc[r] = fmaf(hv.w, w3v, acc[r]);
            }
        }
    }
    if (j < VV) {
        const float bpj = bp[j];
        #pragma unroll
        for (int r = 0; r < 8; ++r) {
            int bg = b0 + ty + 4 * r;
            logits[(size_t)bg * VV + j] = acc[r] + bpj;
        }
    }
}

extern "C" void kernel_launch(void* const* d_in, const int* in_sizes, int n_in,
                              void* d_out, int out_size, void* d_ws, size_t ws_size,
                              hipStream_t stream) {
    const int*   cidx   = (const int*)d_in[0];
    const float* hidden = (const float*)d_in[1];
    const float* carry  = (const float*)d_in[2];
    const float* enc    = (const float*)d_in[3];
    const float* emb    = (const float*)d_in[4];
    const float* w1     = (const float*)d_in[5];
    const float* b1     = (const float*)d_in[6];
    const float* w2     = (const float*)d_in[7];
    const float* b2     = (const float*)d_in[8];
    const float* vvec   = (const float*)d_in[9];
    const float* bv     = (const float*)d_in[10];
    const float* wx     = (const float*)d_in[11];
    const float* wh     = (const float*)d_in[12];
    const float* bl     = (const float*)d_in[13];
    const float* wp     = (const float*)d_in[14];
    const float* bp     = (const float*)d_in[15];

    float* out    = (float*)d_out;
    float* logits = out;
    float* hout   = out + (size_t)BB * VV;
    float* cout   = hout + (size_t)BB * DD;

    float* ws    = (float*)d_ws;
    float* qq    = ws;                         // B*A      = 131072
    float* score = qq + (size_t)BB * AA;       // B*T      = 16384
    float* ctx   = score + (size_t)BB * TT;    // B*E      = 524288
    float* z     = ctx + (size_t)BB * EE;      // B*4D     = 524288

    hipLaunchKernelGGL(k_q,       dim3(BB),                 dim3(256), 0, stream, hidden, w1, b1, b2, qq);
    hipLaunchKernelGGL(k_score,   dim3(TT / 16, BB),        dim3(256), 0, stream, enc, w2, qq, vvec, bv, score);
    hipLaunchKernelGGL(k_context, dim3(2, BB),              dim3(256), 0, stream, enc, score, ctx);
    hipLaunchKernelGGL(k_z,       dim3(N4D / ZBN, BB / ZBM), dim3(256), 0, stream, ctx, emb, cidx, hidden, wx, wh, bl, z);
    hipLaunchKernelGGL(k_gates,   dim3(BB),                 dim3(256), 0, stream, z, carry, hout, cout);
    hipLaunchKernelGGL(k_logits,  dim3((VV + 63) / 64, BB / 32), dim3(256), 0, stream, hout, wp, bp, logits);
}

// Round 3
// 565.886 us; speedup vs baseline: 5.2354x; 1.5896x over previous
//
#include <hip/hip_runtime.h>
#include <hip/hip_bf16.h>
#include <math.h>

#define BB 256
#define TT 64
#define EE 2048
#define DD 512
#define AA 512
#define VV 10000
#define EMBD 256
#define KLSTM (EE + EMBD + DD)   // 2816
#define N4D (4 * DD)             // 2048

using bf16x8 = __attribute__((ext_vector_type(8))) __bf16;
using f32x4  = __attribute__((ext_vector_type(4))) float;

__device__ __forceinline__ float sigf(float x) { return 1.f / (1.f + expf(-x)); }

// ---------------- q = hidden @ w1 + b1 + b2 (fold both biases) ----------------
__global__ void k_q(const float* __restrict__ hidden, const float* __restrict__ w1,
                    const float* __restrict__ b1, const float* __restrict__ b2,
                    float* __restrict__ qq) {
    __shared__ float hs[DD];
    const int b = blockIdx.x, tid = threadIdx.x;
    {
        float2 hv = *(const float2*)&hidden[(size_t)b * DD + 2 * tid];
        hs[2 * tid] = hv.x; hs[2 * tid + 1] = hv.y;
    }
    __syncthreads();
    const int a0 = 2 * tid;
    float2 acc = {0.f, 0.f};
    #pragma unroll 4
    for (int k = 0; k < DD; ++k) {
        float2 w = *(const float2*)&w1[(size_t)k * AA + a0];
        float h = hs[k];
        acc.x = fmaf(h, w.x, acc.x);
        acc.y = fmaf(h, w.y, acc.y);
    }
    qq[(size_t)b * AA + a0]     = acc.x + b1[a0]     + b2[a0];
    qq[(size_t)b * AA + a0 + 1] = acc.y + b1[a0 + 1] + b2[a0 + 1];
}

// ---------------- w2t[n][k] = bf16(w2[k][n])  (2048x512 -> 512x2048) ----------------
__global__ void k_w2t(const float* __restrict__ w2, __bf16* __restrict__ w2t) {
    __shared__ float t[32][33];
    const int k0 = blockIdx.x * 32, n0 = blockIdx.y * 32;
    const int tx = threadIdx.x, ty = threadIdx.y;   // block (32,8)
    #pragma unroll
    for (int i = 0; i < 4; ++i)
        t[ty + 8 * i][tx] = w2[(size_t)(k0 + ty + 8 * i) * AA + n0 + tx];
    __syncthreads();
    #pragma unroll
    for (int i = 0; i < 4; ++i)
        w2t[(size_t)(n0 + ty + 8 * i) * EE + k0 + tx] = (__bf16)t[tx][ty + 8 * i];
}

// ---- score[b,t] = tanh(q[b,:] + enc[b,t,:] @ w2) . v + bv  via bf16 MFMA ----
// grid(T/32=2, B), block(256)=4 waves. M-tile=32 rows (one b), N=512 = 4 waves x 128.
// enc staged f32->bf16 into XOR-swizzled LDS (dbuf); w2t read direct from L2.
__global__ void k_score(const float* __restrict__ enc, const __bf16* __restrict__ w2t,
                        const float* __restrict__ qq, const float* __restrict__ vvec,
                        const float* __restrict__ bv, float* __restrict__ score) {
    __shared__ bf16x8 Abuf[2][32][8];     // [buf][row][granule16], granule ^= row&7
    __shared__ float qs[AA], vs[AA];
    __shared__ float wred[4][32];
    const int b = blockIdx.y, t0 = blockIdx.x * 32;
    const int tid = threadIdx.x;
    const int l = tid & 63, wv = tid >> 6;
    const int n0 = wv * 128;

    qs[tid]       = qq[(size_t)b * AA + tid];
    qs[tid + 256] = qq[(size_t)b * AA + tid + 256];
    vs[tid]       = vvec[tid];
    vs[tid + 256] = vvec[tid + 256];

    // staging: thread -> (row, 16B k-segment)
    const int srow = tid >> 3, skseg = tid & 7;
    const float* encrow = enc + ((size_t)b * TT + t0 + srow) * EE + skseg * 8;
    const int sg = skseg ^ (srow & 7);

    // fragment geometry
    const int ar = l & 15;          // A row / B col within 16
    const int agr = l >> 4;         // k-chunk group (8 bf16 each)
    const __bf16* bbase = w2t + (size_t)(n0 + ar) * EE + agr * 8;

    f32x4 acc[2][8];
    #pragma unroll
    for (int mt = 0; mt < 2; ++mt)
        #pragma unroll
        for (int f = 0; f < 8; ++f)
            acc[mt][f] = (f32x4){0.f, 0.f, 0.f, 0.f};

    // prologue: tile 0 -> buf 0
    {
        float4 u0 = *(const float4*)(encrow);
        float4 u1 = *(const float4*)(encrow + 4);
        bf16x8 pk;
        pk[0] = (__bf16)u0.x; pk[1] = (__bf16)u0.y; pk[2] = (__bf16)u0.z; pk[3] = (__bf16)u0.w;
        pk[4] = (__bf16)u1.x; pk[5] = (__bf16)u1.y; pk[6] = (__bf16)u1.z; pk[7] = (__bf16)u1.w;
        Abuf[0][srow][sg] = pk;
    }
    __syncthreads();

    const int NIT = EE / 64;   // 32
    for (int it = 0; it < NIT; ++it) {
        const int cur = it & 1;
        float4 p0, p1;
        const bool more = (it + 1 < NIT);
        if (more) {
            p0 = *(const float4*)(encrow + (it + 1) * 64);
            p1 = *(const float4*)(encrow + (it + 1) * 64 + 4);
        }
        #pragma unroll
        for (int ks = 0; ks < 2; ++ks) {
            bf16x8 bfr[8];
            #pragma unroll
            for (int f = 0; f < 8; ++f)
                bfr[f] = *(const bf16x8*)(bbase + (size_t)f * 16 * EE + it * 64 + ks * 32);
            bf16x8 a0 = Abuf[cur][ar][(ks * 4 + agr) ^ (ar & 7)];
            bf16x8 a1 = Abuf[cur][16 + ar][(ks * 4 + agr) ^ (ar & 7)];
            #pragma unroll
            for (int f = 0; f < 8; ++f) {
                acc[0][f] = __builtin_amdgcn_mfma_f32_16x16x32_bf16(a0, bfr[f], acc[0][f], 0, 0, 0);
                acc[1][f] = __builtin_amdgcn_mfma_f32_16x16x32_bf16(a1, bfr[f], acc[1][f], 0, 0, 0);
            }
        }
        if (more) {
            bf16x8 pk;
            pk[0] = (__bf16)p0.x; pk[1] = (__bf16)p0.y; pk[2] = (__bf16)p0.z; pk[3] = (__bf16)p0.w;
            pk[4] = (__bf16)p1.x; pk[5] = (__bf16)p1.y; pk[6] = (__bf16)p1.z; pk[7] = (__bf16)p1.w;
            Abuf[cur ^ 1][srow][sg] = pk;
        }
        __syncthreads();
    }

    // epilogue: tanh(q+s)*v, reduce over a (cols)
    float sred[8];
    #pragma unroll
    for (int i = 0; i < 8; ++i) sred[i] = 0.f;
    #pragma unroll
    for (int f = 0; f < 8; ++f) {
        const int a = n0 + f * 16 + ar;
        const float qa = qs[a], va = vs[a];
        #pragma unroll
        for (int mt = 0; mt < 2; ++mt)
            #pragma unroll
            for (int r = 0; r < 4; ++r)
                sred[mt * 4 + r] += tanhf(qa + acc[mt][f][r]) * va;
    }
    #pragma unroll
    for (int i = 0; i < 8; ++i) {
        #pragma unroll
        for (int off = 1; off < 16; off <<= 1)
            sred[i] += __shfl_xor(sred[i], off, 64);
    }
    if (ar == 0) {
        #pragma unroll
        for (int mt = 0; mt < 2; ++mt)
            #pragma unroll
            for (int r = 0; r < 4; ++r)
                wred[wv][mt * 16 + agr * 4 + r] = sred[mt * 4 + r];
    }
    __syncthreads();
    if (tid < 32) {
        float sc = wred[0][tid] + wred[1][tid] + wred[2][tid] + wred[3][tid] + bv[0];
        score[(size_t)b * TT + t0 + tid] = sc;
    }
}

// ---------------- softmax over t + context = sum_t attn * enc ----------------
__global__ void k_context(const float* __restrict__ enc, const float* __restrict__ score,
                          float* __restrict__ ctx) {
    __shared__ float attn[TT];
    const int b = blockIdx.y;
    const int tid = threadIdx.x;
    if (tid < 64) {
        float s = score[(size_t)b * TT + tid];
        float m = s;
        #pragma unroll
        for (int off = 1; off < 64; off <<= 1) m = fmaxf(m, __shfl_xor(m, off, 64));
        float p = expf(s - m);
        float sum = p;
        #pragma unroll
        for (int off = 1; off < 64; off <<= 1) sum += __shfl_xor(sum, off, 64);
        attn[tid] = p / sum;
    }
    __syncthreads();
    const int e = blockIdx.x * 1024 + tid * 4;
    const float* encb = enc + (size_t)b * TT * EE + e;
    float4 acc = {0.f, 0.f, 0.f, 0.f};
    #pragma unroll 4
    for (int t = 0; t < TT; ++t) {
        float a = attn[t];
        float4 ev = *(const float4*)&encb[(size_t)t * EE];
        acc.x = fmaf(a, ev.x, acc.x);
        acc.y = fmaf(a, ev.y, acc.y);
        acc.z = fmaf(a, ev.z, acc.z);
        acc.w = fmaf(a, ev.w, acc.w);
    }
    *(float4*)&ctx[(size_t)b * EE + e] = acc;
}

// ------- z = [ctx, emb[c], hidden] @ [wx; wh] + bl ----------
#define ZBM 32
#define ZBN 64
#define ZBK 64
__global__ void k_z(const float* __restrict__ ctx, const float* __restrict__ emb,
                    const int* __restrict__ cidx, const float* __restrict__ hidden,
                    const float* __restrict__ wx, const float* __restrict__ wh,
                    const float* __restrict__ bl, float* __restrict__ z) {
    __shared__ float As[ZBM][ZBK + 4];
    __shared__ float Ws[ZBK][ZBN];
    __shared__ int cbs[ZBM];
    const int tid = threadIdx.x;
    const int tx = tid & 15, ty = tid >> 4;
    const int j0 = blockIdx.x * ZBN;
    const int b0 = blockIdx.y * ZBM;

    if (tid < ZBM) cbs[tid] = cidx[b0 + tid];

    float4 acc0 = {0.f, 0.f, 0.f, 0.f};
    float4 acc1 = {0.f, 0.f, 0.f, 0.f};

    for (int k0 = 0; k0 < KLSTM; k0 += ZBK) {
        __syncthreads();
        #pragma unroll
        for (int i = 0; i < 8; ++i) {
            int flat = i * 256 + tid;
            int bb = flat >> 6;
            int kk = flat & 63;
            int kg = k0 + kk;
            int bg = b0 + bb;
            float val;
            if (kg < EE)             val = ctx[(size_t)bg * EE + kg];
            else if (kg < EE + EMBD) val = emb[(size_t)cbs[bb] * EMBD + (kg - EE)];
            else                     val = hidden[(size_t)bg * DD + (kg - EE - EMBD)];
            As[bb][kk] = val;
        }
        #pragma unroll
        for (int i = 0; i < 4; ++i) {
            int flat = i * 256 + tid;
            int row = flat >> 4;
            int c4 = flat & 15;
            int kg = k0 + row;
            const float* wrow = (kg < EE + EMBD)
                ? &wx[(size_t)kg * N4D + j0]
                : &wh[(size_t)(kg - EE - EMBD) * N4D + j0];
            *(float4*)&Ws[row][c4 * 4] = *(const float4*)&wrow[c4 * 4];
        }
        __syncthreads();
        #pragma unroll 4
        for (int kk = 0; kk < ZBK; kk += 4) {
            float4 a0 = *(const float4*)&As[2 * ty][kk];
            float4 a1 = *(const float4*)&As[2 * ty + 1][kk];
            const float a0v[4] = {a0.x, a0.y, a0.z, a0.w};
            const float a1v[4] = {a1.x, a1.y, a1.z, a1.w};
            #pragma unroll
            for (int u = 0; u < 4; ++u) {
                float4 w = *(const float4*)&Ws[kk + u][4 * tx];
                acc0.x = fmaf(a0v[u], w.x, acc0.x);
                acc0.y = fmaf(a0v[u], w.y, acc0.y);
                acc0.z = fmaf(a0v[u], w.z, acc0.z);
                acc0.w = fmaf(a0v[u], w.w, acc0.w);
                acc1.x = fmaf(a1v[u], w.x, acc1.x);
                acc1.y = fmaf(a1v[u], w.y, acc1.y);
                acc1.z = fmaf(a1v[u], w.z, acc1.z);
                acc1.w = fmaf(a1v[u], w.w, acc1.w);
            }
        }
    }

    const int j = j0 + 4 * tx;
    float4 bb4 = *(const float4*)&bl[j];
    acc0.x += bb4.x; acc0.y += bb4.y; acc0.z += bb4.z; acc0.w += bb4.w;
    acc1.x += bb4.x; acc1.y += bb4.y; acc1.z += bb4.z; acc1.w += bb4.w;
    *(float4*)&z[(size_t)(b0 + 2 * ty) * N4D + j]     = acc0;
    *(float4*)&z[(size_t)(b0 + 2 * ty + 1) * N4D + j] = acc1;
}

// ---------------- LSTM gates ----------------
__global__ void k_gates(const float* __restrict__ z, const float* __restrict__ carry,
                        float* __restrict__ hout, float* __restrict__ cout) {
    const int b = blockIdx.x, tid = threadIdx.x;
    #pragma unroll
    for (int r = 0; r < 2; ++r) {
        int d = tid + r * 256;
        float zi = z[(size_t)b * N4D + d];
        float zf = z[(size_t)b * N4D + DD + d];
        float zg = z[(size_t)b * N4D + 2 * DD + d];
        float zo = z[(size_t)b * N4D + 3 * DD + d];
        float c = carry[(size_t)b * DD + d];
        float cn = sigf(zf) * c + sigf(zi) * tanhf(zg);
        float hn = sigf(zo) * tanhf(cn);
        cout[(size_t)b * DD + d] = cn;
        hout[(size_t)b * DD + d] = hn;
    }
}

// ---------------- logits = h_new @ wp + bp ----------------
__global__ void k_logits(const float* __restrict__ hnew, const float* __restrict__ wp,
                         const float* __restrict__ bp, float* __restrict__ logits) {
    __shared__ float hs[32][64];
    const int j0 = blockIdx.x * 64;
    const int b0 = blockIdx.y * 32;
    const int tid = threadIdx.x;
    const int tx = tid & 63, ty = tid >> 6;
    const int j = j0 + tx;
    const int jc = (j < VV) ? j : (VV - 1);

    float acc[8];
    #pragma unroll
    for (int r = 0; r < 8; ++r) acc[r] = 0.f;

    for (int k0 = 0; k0 < DD; k0 += 64) {
        __syncthreads();
        #pragma unroll
        for (int r = 0; r < 8; ++r) {
            int flat = r * 256 + tid;
            int bb = flat >> 6;
            int kk = flat & 63;
            hs[bb][kk] = hnew[(size_t)(b0 + bb) * DD + k0 + kk];
        }
        __syncthreads();
        for (int kk = 0; kk < 64; kk += 4) {
            int kg = k0 + kk;
            float w0  = wp[(size_t)kg * VV + jc];
            float w1v = wp[(size_t)(kg + 1) * VV + jc];
            float w2v = wp[(size_t)(kg + 2) * VV + jc];
            float w3v = wp[(size_t)(kg + 3) * VV + jc];
            #pragma unroll
            for (int r = 0; r < 8; ++r) {
                int bb = ty + 4 * r;
                float4 hv = *(const float4*)&hs[bb][kk];
                acc[r] = fmaf(hv.x, w0, acc[r]);
                acc[r] = fmaf(hv.y, w1v, acc[r]);
                acc[r] = fmaf(hv.z, w2v, acc[r]);
                acc[r] = fmaf(hv.w, w3v, acc[r]);
            }
        }
    }
    if (j < VV) {
        const float bpj = bp[j];
        #pragma unroll
        for (int r = 0; r < 8; ++r) {
            int bg = b0 + ty + 4 * r;
            logits[(size_t)bg * VV + j] = acc[r] + bpj;
        }
    }
}

extern "C" void kernel_launch(void* const* d_in, const int* in_sizes, int n_in,
                              void* d_out, int out_size, void* d_ws, size_t ws_size,
                              hipStream_t stream) {
    const int*   cidx   = (const int*)d_in[0];
    const float* hidden = (const float*)d_in[1];
    const float* carry  = (const float*)d_in[2];
    const float* enc    = (const float*)d_in[3];
    const float* emb    = (const float*)d_in[4];
    const float* w1     = (const float*)d_in[5];
    const float* b1     = (const float*)d_in[6];
    const float* w2     = (const float*)d_in[7];
    const float* b2     = (const float*)d_in[8];
    const float* vvec   = (const float*)d_in[9];
    const float* bv     = (const float*)d_in[10];
    const float* wx     = (const float*)d_in[11];
    const float* wh     = (const float*)d_in[12];
    const float* bl     = (const float*)d_in[13];
    const float* wp     = (const float*)d_in[14];
    const float* bp     = (const float*)d_in[15];

    float* out    = (float*)d_out;
    float* logits = out;
    float* hout   = out + (size_t)BB * VV;
    float* cout   = hout + (size_t)BB * DD;

    float* ws    = (float*)d_ws;
    float* qq    = ws;                         // B*A   = 131072 f32
    float* score = qq + (size_t)BB * AA;       // B*T   = 16384 f32
    float* ctx   = score + (size_t)BB * TT;    // B*E   = 524288 f32
    float* z     = ctx + (size_t)BB * EE;      // B*4D  = 524288 f32
    // w2t (512x2048 bf16 = 2 MB) aliases ctx: consumed by k_score BEFORE k_context writes ctx
    __bf16* w2t  = (__bf16*)ctx;

    hipLaunchKernelGGL(k_w2t,     dim3(EE / 32, AA / 32),   dim3(32, 8), 0, stream, w2, w2t);
    hipLaunchKernelGGL(k_q,       dim3(BB),                 dim3(256), 0, stream, hidden, w1, b1, b2, qq);
    hipLaunchKernelGGL(k_score,   dim3(TT / 32, BB),        dim3(256), 0, stream, enc, w2t, qq, vvec, bv, score);
    hipLaunchKernelGGL(k_context, dim3(2, BB),              dim3(256), 0, stream, enc, score, ctx);
    hipLaunchKernelGGL(k_z,       dim3(N4D / ZBN, BB / ZBM), dim3(256), 0, stream, ctx, emb, cidx, hidden, wx, wh, bl, z);
    hipLaunchKernelGGL(k_gates,   dim3(BB),                 dim3(256), 0, stream, z, carry, hout, cout);
    hipLaunchKernelGGL(k_logits,  dim3((VV + 63) / 64, BB / 32), dim3(256), 0, stream, hout, wp, bp, logits);
}

// Round 4
// 346.615 us; speedup vs baseline: 8.5473x; 1.6326x over previous
//
#include <hip/hip_runtime.h>
#include <hip/hip_bf16.h>
#include <math.h>

#define BB 256
#define TT 64
#define EE 2048
#define DD 512
#define AA 512
#define VV 10000
#define EMBD 256
#define KLSTM (EE + EMBD + DD)   // 2816
#define N4D (4 * DD)             // 2048

using bf16x8 = __attribute__((ext_vector_type(8))) __bf16;
using f32x4  = __attribute__((ext_vector_type(4))) float;

__device__ __forceinline__ float sigf(float x) { return 1.f / (1.f + expf(-x)); }

// ---------------- q = hidden @ w1 + b1 + b2 (fold both biases) ----------------
__global__ void k_q(const float* __restrict__ hidden, const float* __restrict__ w1,
                    const float* __restrict__ b1, const float* __restrict__ b2,
                    float* __restrict__ qq) {
    __shared__ float hs[DD];
    const int b = blockIdx.x, tid = threadIdx.x;
    {
        float2 hv = *(const float2*)&hidden[(size_t)b * DD + 2 * tid];
        hs[2 * tid] = hv.x; hs[2 * tid + 1] = hv.y;
    }
    __syncthreads();
    const int a0 = 2 * tid;
    float2 acc = {0.f, 0.f};
    #pragma unroll 4
    for (int k = 0; k < DD; ++k) {
        float2 w = *(const float2*)&w1[(size_t)k * AA + a0];
        float h = hs[k];
        acc.x = fmaf(h, w.x, acc.x);
        acc.y = fmaf(h, w.y, acc.y);
    }
    qq[(size_t)b * AA + a0]     = acc.x + b1[a0]     + b2[a0];
    qq[(size_t)b * AA + a0 + 1] = acc.y + b1[a0 + 1] + b2[a0 + 1];
}

// ---------------- w2t[n][k] = bf16(w2[k][n])  (2048x512 -> 512x2048) ----------------
__global__ void k_w2t(const float* __restrict__ w2, __bf16* __restrict__ w2t) {
    __shared__ float t[32][33];
    const int k0 = blockIdx.x * 32, n0 = blockIdx.y * 32;
    const int tx = threadIdx.x, ty = threadIdx.y;   // block (32,8)
    #pragma unroll
    for (int i = 0; i < 4; ++i)
        t[ty + 8 * i][tx] = w2[(size_t)(k0 + ty + 8 * i) * AA + n0 + tx];
    __syncthreads();
    #pragma unroll
    for (int i = 0; i < 4; ++i)
        w2t[(size_t)(n0 + ty + 8 * i) * EE + k0 + tx] = (__bf16)t[tx][ty + 8 * i];
}

// ------- wxh_t[n][k] = bf16( k<2304 ? wx[k][n] : wh[k-2304][n] ), n<2048, k<2816 -------
__global__ void k_wxht(const float* __restrict__ wx, const float* __restrict__ wh,
                       __bf16* __restrict__ wt) {
    __shared__ float t[32][33];
    const int k0 = blockIdx.x * 32, n0 = blockIdx.y * 32;
    const int tx = threadIdx.x, ty = threadIdx.y;   // block (32,8)
    #pragma unroll
    for (int i = 0; i < 4; ++i) {
        int k = k0 + ty + 8 * i;
        const float* wrow = (k < EE + EMBD) ? &wx[(size_t)k * N4D] : &wh[(size_t)(k - EE - EMBD) * N4D];
        t[ty + 8 * i][tx] = wrow[n0 + tx];
    }
    __syncthreads();
    #pragma unroll
    for (int i = 0; i < 4; ++i)
        wt[(size_t)(n0 + ty + 8 * i) * KLSTM + k0 + tx] = (__bf16)t[tx][ty + 8 * i];
}

// ---- score[b,t] = tanh(q[b,:] + enc[b,t,:] @ w2) . v + bv  via bf16 MFMA ----
__global__ void k_score(const float* __restrict__ enc, const __bf16* __restrict__ w2t,
                        const float* __restrict__ qq, const float* __restrict__ vvec,
                        const float* __restrict__ bv, float* __restrict__ score) {
    __shared__ bf16x8 Abuf[2][32][8];     // [buf][row][granule16], granule ^= row&7
    __shared__ float qs[AA], vs[AA];
    __shared__ float wred[4][32];
    const int b = blockIdx.y, t0 = blockIdx.x * 32;
    const int tid = threadIdx.x;
    const int l = tid & 63, wv = tid >> 6;
    const int n0 = wv * 128;

    qs[tid]       = qq[(size_t)b * AA + tid];
    qs[tid + 256] = qq[(size_t)b * AA + tid + 256];
    vs[tid]       = vvec[tid];
    vs[tid + 256] = vvec[tid + 256];

    const int srow = tid >> 3, skseg = tid & 7;
    const float* encrow = enc + ((size_t)b * TT + t0 + srow) * EE + skseg * 8;
    const int sg = skseg ^ (srow & 7);

    const int ar = l & 15;
    const int agr = l >> 4;
    const __bf16* bbase = w2t + (size_t)(n0 + ar) * EE + agr * 8;

    f32x4 acc[2][8];
    #pragma unroll
    for (int mt = 0; mt < 2; ++mt)
        #pragma unroll
        for (int f = 0; f < 8; ++f)
            acc[mt][f] = (f32x4){0.f, 0.f, 0.f, 0.f};

    {
        float4 u0 = *(const float4*)(encrow);
        float4 u1 = *(const float4*)(encrow + 4);
        bf16x8 pk;
        pk[0] = (__bf16)u0.x; pk[1] = (__bf16)u0.y; pk[2] = (__bf16)u0.z; pk[3] = (__bf16)u0.w;
        pk[4] = (__bf16)u1.x; pk[5] = (__bf16)u1.y; pk[6] = (__bf16)u1.z; pk[7] = (__bf16)u1.w;
        Abuf[0][srow][sg] = pk;
    }
    __syncthreads();

    const int NIT = EE / 64;   // 32
    for (int it = 0; it < NIT; ++it) {
        const int cur = it & 1;
        float4 p0, p1;
        const bool more = (it + 1 < NIT);
        if (more) {
            p0 = *(const float4*)(encrow + (it + 1) * 64);
            p1 = *(const float4*)(encrow + (it + 1) * 64 + 4);
        }
        #pragma unroll
        for (int ks = 0; ks < 2; ++ks) {
            bf16x8 bfr[8];
            #pragma unroll
            for (int f = 0; f < 8; ++f)
                bfr[f] = *(const bf16x8*)(bbase + (size_t)f * 16 * EE + it * 64 + ks * 32);
            bf16x8 a0 = Abuf[cur][ar][(ks * 4 + agr) ^ (ar & 7)];
            bf16x8 a1 = Abuf[cur][16 + ar][(ks * 4 + agr) ^ (ar & 7)];
            #pragma unroll
            for (int f = 0; f < 8; ++f) {
                acc[0][f] = __builtin_amdgcn_mfma_f32_16x16x32_bf16(a0, bfr[f], acc[0][f], 0, 0, 0);
                acc[1][f] = __builtin_amdgcn_mfma_f32_16x16x32_bf16(a1, bfr[f], acc[1][f], 0, 0, 0);
            }
        }
        if (more) {
            bf16x8 pk;
            pk[0] = (__bf16)p0.x; pk[1] = (__bf16)p0.y; pk[2] = (__bf16)p0.z; pk[3] = (__bf16)p0.w;
            pk[4] = (__bf16)p1.x; pk[5] = (__bf16)p1.y; pk[6] = (__bf16)p1.z; pk[7] = (__bf16)p1.w;
            Abuf[cur ^ 1][srow][sg] = pk;
        }
        __syncthreads();
    }

    float sred[8];
    #pragma unroll
    for (int i = 0; i < 8; ++i) sred[i] = 0.f;
    #pragma unroll
    for (int f = 0; f < 8; ++f) {
        const int a = n0 + f * 16 + ar;
        const float qa = qs[a], va = vs[a];
        #pragma unroll
        for (int mt = 0; mt < 2; ++mt)
            #pragma unroll
            for (int r = 0; r < 4; ++r)
                sred[mt * 4 + r] += tanhf(qa + acc[mt][f][r]) * va;
    }
    #pragma unroll
    for (int i = 0; i < 8; ++i) {
        #pragma unroll
        for (int off = 1; off < 16; off <<= 1)
            sred[i] += __shfl_xor(sred[i], off, 64);
    }
    if (ar == 0) {
        #pragma unroll
        for (int mt = 0; mt < 2; ++mt)
            #pragma unroll
            for (int r = 0; r < 4; ++r)
                wred[wv][mt * 16 + agr * 4 + r] = sred[mt * 4 + r];
    }
    __syncthreads();
    if (tid < 32) {
        float sc = wred[0][tid] + wred[1][tid] + wred[2][tid] + wred[3][tid] + bv[0];
        score[(size_t)b * TT + t0 + tid] = sc;
    }
}

// ---------------- softmax over t + context = sum_t attn * enc ----------------
__global__ void k_context(const float* __restrict__ enc, const float* __restrict__ score,
                          float* __restrict__ ctx) {
    __shared__ float attn[TT];
    const int b = blockIdx.y;
    const int tid = threadIdx.x;
    if (tid < 64) {
        float s = score[(size_t)b * TT + tid];
        float m = s;
        #pragma unroll
        for (int off = 1; off < 64; off <<= 1) m = fmaxf(m, __shfl_xor(m, off, 64));
        float p = expf(s - m);
        float sum = p;
        #pragma unroll
        for (int off = 1; off < 64; off <<= 1) sum += __shfl_xor(sum, off, 64);
        attn[tid] = p / sum;
    }
    __syncthreads();
    const int e = blockIdx.x * 1024 + tid * 4;
    const float* encb = enc + (size_t)b * TT * EE + e;
    float4 acc = {0.f, 0.f, 0.f, 0.f};
    #pragma unroll 4
    for (int t = 0; t < TT; ++t) {
        float a = attn[t];
        float4 ev = *(const float4*)&encb[(size_t)t * EE];
        acc.x = fmaf(a, ev.x, acc.x);
        acc.y = fmaf(a, ev.y, acc.y);
        acc.z = fmaf(a, ev.z, acc.z);
        acc.w = fmaf(a, ev.w, acc.w);
    }
    *(float4*)&ctx[(size_t)b * EE + e] = acc;
}

// ------- z = [ctx, emb[c], hidden] @ [wx; wh] via bf16 MFMA, K split 4 ways -------
// grid(8 nb, 8 mb, 4 ks), block 256 = 4 waves. Tile: M=32, N=256 (wave n-slice 64).
// A-chunk (32 x 704) staged once to swizzled LDS; no barriers in K loop.
// B-frags prefetched one iter ahead (register ping-pong, unroll-2).
#define ZKS 4
#define ZKC (KLSTM / ZKS)    // 704
#define ZNIT (ZKC / 32)      // 22
__global__ void k_z(const float* __restrict__ ctx, const float* __restrict__ emb,
                    const int* __restrict__ cidx, const float* __restrict__ hidden,
                    const __bf16* __restrict__ wt, float* __restrict__ zp) {
    __shared__ bf16x8 Abuf[32][ZKC / 8];   // [row][granule], granule ^= row&7 (45 KB)
    __shared__ int cbs[32];
    const int tid = threadIdx.x;
    const int l = tid & 63, wv = tid >> 6;
    const int b0  = blockIdx.y * 32;
    const int kc0 = blockIdx.z * ZKC;
    const int nw  = blockIdx.x * 256 + wv * 64;

    if (tid < 32) cbs[tid] = cidx[b0 + tid];
    __syncthreads();

    // stage A: thread -> row = tid>>3, granules g0, g0+8, ..., g0+80
    {
        const int srow = tid >> 3, g0 = tid & 7;
        const int bg = b0 + srow;
        const int erow = cbs[srow];
        #pragma unroll
        for (int i = 0; i < 11; ++i) {
            int g = g0 + 8 * i;
            int k = kc0 + g * 8;
            const float* src;
            if (k < EE)            src = &ctx[(size_t)bg * EE + k];
            else if (k < EE + EMBD) src = &emb[(size_t)erow * EMBD + (k - EE)];
            else                    src = &hidden[(size_t)bg * DD + (k - EE - EMBD)];
            float4 u0 = *(const float4*)src;
            float4 u1 = *(const float4*)(src + 4);
            bf16x8 pk;
            pk[0] = (__bf16)u0.x; pk[1] = (__bf16)u0.y; pk[2] = (__bf16)u0.z; pk[3] = (__bf16)u0.w;
            pk[4] = (__bf16)u1.x; pk[5] = (__bf16)u1.y; pk[6] = (__bf16)u1.z; pk[7] = (__bf16)u1.w;
            Abuf[srow][g ^ (srow & 7)] = pk;
        }
    }
    __syncthreads();

    const int ar = l & 15, agr = l >> 4;
    const __bf16* bbase = wt + (size_t)(nw + ar) * KLSTM + kc0 + agr * 8;

    f32x4 acc[2][4];
    #pragma unroll
    for (int mt = 0; mt < 2; ++mt)
        #pragma unroll
        for (int f = 0; f < 4; ++f)
            acc[mt][f] = (f32x4){0.f, 0.f, 0.f, 0.f};

    bf16x8 bA[4], bBv[4];
    #pragma unroll
    for (int f = 0; f < 4; ++f)
        bA[f] = *(const bf16x8*)(bbase + (size_t)f * 16 * KLSTM);

    for (int itp = 0; itp < ZNIT / 2; ++itp) {
        const int it0 = 2 * itp, it1 = 2 * itp + 1;
        // phase 0: prefetch it1 into bBv, compute it0 with bA
        #pragma unroll
        for (int f = 0; f < 4; ++f)
            bBv[f] = *(const bf16x8*)(bbase + (size_t)f * 16 * KLSTM + it1 * 32);
        {
            bf16x8 a0 = Abuf[ar][(it0 * 4 + agr) ^ (ar & 7)];
            bf16x8 a1 = Abuf[16 + ar][(it0 * 4 + agr) ^ (ar & 7)];
            #pragma unroll
            for (int f = 0; f < 4; ++f) {
                acc[0][f] = __builtin_amdgcn_mfma_f32_16x16x32_bf16(a0, bA[f], acc[0][f], 0, 0, 0);
                acc[1][f] = __builtin_amdgcn_mfma_f32_16x16x32_bf16(a1, bA[f], acc[1][f], 0, 0, 0);
            }
        }
        // phase 1: prefetch it0+2 into bA (clamped), compute it1 with bBv
        const int it2 = (it1 + 1 < ZNIT) ? it1 + 1 : it1;
        #pragma unroll
        for (int f = 0; f < 4; ++f)
            bA[f] = *(const bf16x8*)(bbase + (size_t)f * 16 * KLSTM + it2 * 32);
        {
            bf16x8 a0 = Abuf[ar][(it1 * 4 + agr) ^ (ar & 7)];
            bf16x8 a1 = Abuf[16 + ar][(it1 * 4 + agr) ^ (ar & 7)];
            #pragma unroll
            for (int f = 0; f < 4; ++f) {
                acc[0][f] = __builtin_amdgcn_mfma_f32_16x16x32_bf16(a0, bBv[f], acc[0][f], 0, 0, 0);
                acc[1][f] = __builtin_amdgcn_mfma_f32_16x16x32_bf16(a1, bBv[f], acc[1][f], 0, 0, 0);
            }
        }
    }

    float* zpo = zp + (size_t)blockIdx.z * BB * N4D;
    #pragma unroll
    for (int mt = 0; mt < 2; ++mt)
        #pragma unroll
        for (int f = 0; f < 4; ++f)
            #pragma unroll
            for (int r = 0; r < 4; ++r)
                zpo[(size_t)(b0 + mt * 16 + agr * 4 + r) * N4D + nw + f * 16 + ar] = acc[mt][f][r];
}

// ---------------- LSTM gates: sum K-split partials + bias, then activations ----------------
__global__ void k_gates(const float* __restrict__ zp, const float* __restrict__ carry,
                        const float* __restrict__ bl,
                        float* __restrict__ hout, float* __restrict__ cout) {
    const int b = blockIdx.x, tid = threadIdx.x;
    const size_t P = (size_t)BB * N4D;
    #pragma unroll
    for (int r = 0; r < 2; ++r) {
        int d = tid + r * 256;
        float zi = bl[d], zf = bl[DD + d], zg = bl[2 * DD + d], zo = bl[3 * DD + d];
        #pragma unroll
        for (int ks = 0; ks < ZKS; ++ks) {
            const float* zb = zp + ks * P + (size_t)b * N4D;
            zi += zb[d];
            zf += zb[DD + d];
            zg += zb[2 * DD + d];
            zo += zb[3 * DD + d];
        }
        float c = carry[(size_t)b * DD + d];
        float cn = sigf(zf) * c + sigf(zi) * tanhf(zg);
        float hn = sigf(zo) * tanhf(cn);
        cout[(size_t)b * DD + d] = cn;
        hout[(size_t)b * DD + d] = hn;
    }
}

// ---------------- logits = h_new @ wp + bp ----------------
__global__ void k_logits(const float* __restrict__ hnew, const float* __restrict__ wp,
                         const float* __restrict__ bp, float* __restrict__ logits) {
    __shared__ float hs[32][64];
    const int j0 = blockIdx.x * 64;
    const int b0 = blockIdx.y * 32;
    const int tid = threadIdx.x;
    const int tx = tid & 63, ty = tid >> 6;
    const int j = j0 + tx;
    const int jc = (j < VV) ? j : (VV - 1);

    float acc[8];
    #pragma unroll
    for (int r = 0; r < 8; ++r) acc[r] = 0.f;

    for (int k0 = 0; k0 < DD; k0 += 64) {
        __syncthreads();
        #pragma unroll
        for (int r = 0; r < 8; ++r) {
            int flat = r * 256 + tid;
            int bb = flat >> 6;
            int kk = flat & 63;
            hs[bb][kk] = hnew[(size_t)(b0 + bb) * DD + k0 + kk];
        }
        __syncthreads();
        for (int kk = 0; kk < 64; kk += 4) {
            int kg = k0 + kk;
            float w0  = wp[(size_t)kg * VV + jc];
            float w1v = wp[(size_t)(kg + 1) * VV + jc];
            float w2v = wp[(size_t)(kg + 2) * VV + jc];
            float w3v = wp[(size_t)(kg + 3) * VV + jc];
            #pragma unroll
            for (int r = 0; r < 8; ++r) {
                int bb = ty + 4 * r;
                float4 hv = *(const float4*)&hs[bb][kk];
                acc[r] = fmaf(hv.x, w0, acc[r]);
                acc[r] = fmaf(hv.y, w1v, acc[r]);
                acc[r] = fmaf(hv.z, w2v, acc[r]);
                acc[r] = fmaf(hv.w, w3v, acc[r]);
            }
        }
    }
    if (j < VV) {
        const float bpj = bp[j];
        #pragma unroll
        for (int r = 0; r < 8; ++r) {
            int bg = b0 + ty + 4 * r;
            logits[(size_t)bg * VV + j] = acc[r] + bpj;
        }
    }
}

extern "C" void kernel_launch(void* const* d_in, const int* in_sizes, int n_in,
                              void* d_out, int out_size, void* d_ws, size_t ws_size,
                              hipStream_t stream) {
    const int*   cidx   = (const int*)d_in[0];
    const float* hidden = (const float*)d_in[1];
    const float* carry  = (const float*)d_in[2];
    const float* enc    = (const float*)d_in[3];
    const float* emb    = (const float*)d_in[4];
    const float* w1     = (const float*)d_in[5];
    const float* b1     = (const float*)d_in[6];
    const float* w2     = (const float*)d_in[7];
    const float* b2     = (const float*)d_in[8];
    const float* vvec   = (const float*)d_in[9];
    const float* bv     = (const float*)d_in[10];
    const float* wx     = (const float*)d_in[11];
    const float* wh     = (const float*)d_in[12];
    const float* bl     = (const float*)d_in[13];
    const float* wp     = (const float*)d_in[14];
    const float* bp     = (const float*)d_in[15];

    float* out    = (float*)d_out;
    float* logits = out;
    float* hout   = out + (size_t)BB * VV;
    float* cout   = hout + (size_t)BB * DD;

    float* ws    = (float*)d_ws;
    float* qq    = ws;                          // B*A            = 131072 f32
    float* score = qq + (size_t)BB * AA;        // B*T            = 16384 f32
    float* ctx   = score + (size_t)BB * TT;     // B*E            = 524288 f32
    float* zp    = ctx + (size_t)BB * EE;       // ZKS*B*4D       = 2097152 f32
    __bf16* wxh_t = (__bf16*)(zp + (size_t)ZKS * BB * N4D);   // 2048*2816 bf16 = 11.5 MB
    // w2t (512x2048 bf16 = 2 MB) aliases ctx: consumed by k_score BEFORE k_context writes ctx
    __bf16* w2t  = (__bf16*)ctx;

    hipLaunchKernelGGL(k_w2t,     dim3(EE / 32, AA / 32),    dim3(32, 8), 0, stream, w2, w2t);
    hipLaunchKernelGGL(k_wxht,    dim3(KLSTM / 32, N4D / 32), dim3(32, 8), 0, stream, wx, wh, wxh_t);
    hipLaunchKernelGGL(k_q,       dim3(BB),                  dim3(256), 0, stream, hidden, w1, b1, b2, qq);
    hipLaunchKernelGGL(k_score,   dim3(TT / 32, BB),         dim3(256), 0, stream, enc, w2t, qq, vvec, bv, score);
    hipLaunchKernelGGL(k_context, dim3(2, BB),               dim3(256), 0, stream, enc, score, ctx);
    hipLaunchKernelGGL(k_z,       dim3(N4D / 256, BB / 32, ZKS), dim3(256), 0, stream, ctx, emb, cidx, hidden, wxh_t, zp);
    hipLaunchKernelGGL(k_gates,   dim3(BB),                  dim3(256), 0, stream, zp, carry, bl, hout, cout);
    hipLaunchKernelGGL(k_logits,  dim3((VV + 63) / 64, BB / 32), dim3(256), 0, stream, hout, wp, bp, logits);
}